// Round 12
// baseline (2031.112 us; speedup 1.0000x reference)
//
#include <hip/hip_runtime.h>
#include <cstdint>
#include <cstddef>

#define B_ 4
#define T_ 24
#define N_ 512

// gate nonlinearities: evaluate in f64, round once to f32 (R4-proven numerics)
__device__ __forceinline__ float fsig(float x)  { return (float)(1.0 / (1.0 + exp(-(double)x))); }
__device__ __forceinline__ float ftanh(float x) { return (float)tanh((double)x); }

// 16-slot XOR swizzle for [F][64] LDS tiles (R7-proven)
__device__ __forceinline__ int swz16(int f) { return (((f & 15) ^ ((f >> 4) & 15)) << 2); }

// ================= PRECOMPUTE (parallel, recurrence-free) =================

// xp = relu(x @ fc_w + fc_b), stored feature-major xpT[bt][f][node]
__global__ __launch_bounds__(256) void xpT_kernel(const float* __restrict__ x,
                                                  const float* __restrict__ fc_w,
                                                  const float* __restrict__ fc_b,
                                                  float* __restrict__ xpT) {
    __shared__ __align__(16) float sX[64 * 68];
    __shared__ __align__(16) float sW[64 * 64];
    __shared__ float sB[64];
    const int bt = blockIdx.y;
    const int n0 = blockIdx.x * 64;
    const int tid = threadIdx.x;
    for (int i = tid * 4; i < 4096; i += 1024)
        *(float4*)&sW[i] = *(const float4*)&fc_w[i];
    if (tid < 64) sB[tid] = fc_b[tid];
    {
        int r = tid >> 2, kq = (tid & 3) * 16;
        const float* p = x + ((size_t)bt * N_ + n0 + r) * 64 + kq;
        #pragma unroll
        for (int j = 0; j < 4; ++j)
            *(float4*)&sX[r * 68 + kq + j * 4] = *(const float4*)(p + j * 4);
    }
    __syncthreads();
    const int f = tid & 63, ng = tid >> 6;
    float d[16];
    #pragma unroll
    for (int j = 0; j < 16; ++j) d[j] = 0.f;
    for (int k = 0; k < 64; ++k) {
        float w = sW[k * 64 + f];
        #pragma unroll
        for (int j = 0; j < 16; ++j)
            d[j] = fmaf(sX[(ng * 16 + j) * 68 + k], w, d[j]);
    }
    const float bias = sB[f];
    float* o = xpT + ((size_t)bt * 64 + f) * N_ + n0 + ng * 16;
    #pragma unroll
    for (int j = 0; j < 16; ++j)
        o[j] = fmaxf(__fadd_rn(d[j], bias), 0.f);
}

// UX[bt][node][64] = (A_bt @ xp_bt): 64x64 block tile, 4x4 register tiling (R11-proven)
__global__ __launch_bounds__(256) void ux_kernel(const float* __restrict__ e,
                                                 const float* __restrict__ xpT,
                                                 float* __restrict__ UX) {
    __shared__ __align__(16) float sA[2][64 * 72];
    __shared__ __align__(16) float sV[2][64 * 64];
    const int bt = blockIdx.y;
    const int m0 = blockIdx.x * 64;
    const int tid = threadIdx.x;
    const float* Ab = e + ((size_t)bt * N_ + m0) * N_;
    const float* s0 = xpT + (size_t)bt * 64 * N_;

    auto stageA = [&](float* dst, int kt) {
        const int r = tid >> 2, kq = (tid & 3) * 16;
        const float* src = Ab + (size_t)r * N_ + kt * 64 + kq;
        float* d = dst + r * 72 + kq;
        #pragma unroll
        for (int j = 0; j < 4; ++j)
            *(float4*)(d + j * 4) = *(const float4*)(src + j * 4);
    };
    auto stageV = [&](float* dst, int kt) {
        const int f = tid >> 2, q = tid & 3;
        const int sw = swz16(f);
        const float* src = s0 + (size_t)f * N_ + kt * 64;
        #pragma unroll
        for (int j = 0; j < 4; ++j) {
            int k = q * 16 + j * 4;
            *(float4*)&dst[f * 64 + (k ^ sw)] = *(const float4*)(src + k);
        }
    };

    stageA(sA[0], 0);
    stageV(sV[0], 0);
    __syncthreads();

    const int cg = tid & 15, rg = tid >> 4;
    const int c0 = cg * 4;
    float acc[4][4];
    #pragma unroll
    for (int i = 0; i < 4; ++i)
        #pragma unroll
        for (int j = 0; j < 4; ++j) acc[i][j] = 0.f;

    for (int kb = 0; kb < 8; ++kb) {
        if (kb < 7) { stageA(sA[(kb + 1) & 1], kb + 1); stageV(sV[(kb + 1) & 1], kb + 1); }
        const float* Ab_ = sA[kb & 1];
        const float* Vb_ = sV[kb & 1];
        #pragma unroll 4
        for (int kg = 0; kg < 16; ++kg) {
            const int k = kg * 4;
            float4 v[4], a[4];
            #pragma unroll
            for (int j = 0; j < 4; ++j)
                v[j] = *(const float4*)&Vb_[(c0 + j) * 64 + (k ^ swz16(c0 + j))];
            #pragma unroll
            for (int i = 0; i < 4; ++i)
                a[i] = *(const float4*)&Ab_[(rg * 4 + i) * 72 + k];
            #pragma unroll
            for (int i = 0; i < 4; ++i)
                #pragma unroll
                for (int j = 0; j < 4; ++j) {
                    acc[i][j] = fmaf(a[i].x, v[j].x, acc[i][j]);
                    acc[i][j] = fmaf(a[i].y, v[j].y, acc[i][j]);
                    acc[i][j] = fmaf(a[i].z, v[j].z, acc[i][j]);
                    acc[i][j] = fmaf(a[i].w, v[j].w, acc[i][j]);
                }
        }
        __syncthreads();
    }
    #pragma unroll
    for (int i = 0; i < 4; ++i)
        *(float4*)&UX[((size_t)bt * N_ + m0 + rg * 4 + i) * 64 + c0] =
            make_float4(acc[i][0], acc[i][1], acc[i][2], acc[i][3]);
}

// ================= STAGE KERNELS (BM=8, 256 blocks; S2: 256 thr, else 128 thr) =================
// S1: C = A@h;        hz = relu([UX|C]@Wz1); hr = relu([UX|C]@Wr1)
// S2: C = A@[hz|hr];  z = sig(C_z@Wz2) -> zT; rh = sig(C_r@Wr2)*h
// S3: C = A@rh;       hc = relu(UX@Wc1_top + C@Wc1_bot)
// S4: C = A@hc;       c = tanh(C@Wc2); hn = z*h + (1-z)*c -> hT, out
template <int STAGE>
__global__ __launch_bounds__((STAGE == 2) ? 256 : 128) void stage_kernel(
    const float* __restrict__ e, int t,
    const float* __restrict__ UX,
    const float* __restrict__ Wz1, const float* __restrict__ Wz2,
    const float* __restrict__ Wr1, const float* __restrict__ Wr2,
    const float* __restrict__ Wc1, const float* __restrict__ Wc2,
    float* __restrict__ hT, float* __restrict__ hzT, float* __restrict__ hrT,
    float* __restrict__ zT, float* __restrict__ rhT, float* __restrict__ hcT,
    float* __restrict__ out)
{
    constexpr int F  = (STAGE == 2) ? 128 : 64;
    constexpr int NT = (STAGE == 2) ? 256 : 128;
    constexpr int SC = F + 4;
    __shared__ __align__(16) float sA[8 * 512];          // 16 KB
    __shared__ __align__(16) float sV[2 * F * 64];       // 64 KB (F=128) / 32 KB
    __shared__ __align__(16) float sC[8 * SC];
    __shared__ __align__(16) float sUX[8 * 68];

    const int b = blockIdx.y;
    const int m0 = blockIdx.x * 8;
    const int tid = threadIdx.x;
    const int bt = b * T_ + t;

    const float* Ab = e + ((size_t)bt * N_ + m0) * N_;

    const float* s0;
    const float* s1 = nullptr;
    if (STAGE == 1)      { s0 = hT  + (size_t)b * 64 * N_; }
    else if (STAGE == 2) { s0 = hzT + (size_t)b * 64 * N_; s1 = hrT + (size_t)b * 64 * N_; }
    else if (STAGE == 3) { s0 = rhT + (size_t)b * 64 * N_; }
    else                 { s0 = hcT + (size_t)b * 64 * N_; }

    {   // stage A rows [8][512]: 1024 float4 over NT threads
        if constexpr (NT == 256) {
            const int r = tid >> 5, seg = (tid & 31) * 16;
            const float* src = Ab + (size_t)r * N_ + seg;
            float* dst = sA + r * 512 + seg;
            #pragma unroll
            for (int j = 0; j < 4; ++j)
                *(float4*)(dst + j * 4) = *(const float4*)(src + j * 4);
        } else {
            const int r = tid >> 4, seg = (tid & 15) * 32;
            const float* src = Ab + (size_t)r * N_ + seg;
            float* dst = sA + r * 512 + seg;
            #pragma unroll
            for (int j = 0; j < 8; ++j)
                *(float4*)(dst + j * 4) = *(const float4*)(src + j * 4);
        }
    }
    if constexpr (STAGE == 1 || STAGE == 3) {
        // stage UX tile [8][64]: 128 float4, NT=128 -> 1 each
        const int n = tid >> 4, q = (tid & 15) * 4;
        *(float4*)&sUX[n * 68 + q] =
            *(const float4*)&UX[((size_t)bt * N_ + m0 + n) * 64 + q];
    }

    auto stageV = [&](float* dst, int kt) {
        // F*16 float4 over NT threads -> 8 per thread in both cases
        const int f = tid >> 1, h = tid & 1;
        const float* src = ((F == 64 || f < 64) ? (s0 + (size_t)f * N_)
                                                : (s1 + (size_t)(f - 64) * N_)) + kt * 64 + h * 32;
        const int sw = swz16(f);
        #pragma unroll
        for (int j = 0; j < 8; ++j)
            *(float4*)&dst[f * 64 + ((h * 32 + j * 4) ^ sw)] = *(const float4*)(src + j * 4);
    };

    // ---- conv: C = A @ V, 2x2 register tile, double-buffered, ascending-k chains ----
    const int rg = (NT == 256) ? (tid >> 6) : (tid >> 5);   // 0..3
    const int r0 = 2 * rg;
    const int cg = (NT == 256) ? (tid & 63) : (tid & 31);
    const int c0 = (F == 128) ? cg : 2 * cg;
    const int c1 = (F == 128) ? cg + 64 : 2 * cg + 1;
    const int sw0 = swz16(c0), sw1 = swz16(c1);
    float a00 = 0.f, a01 = 0.f, a10 = 0.f, a11 = 0.f;

    stageV(sV, 0);
    __syncthreads();
    for (int kb = 0; kb < 8; ++kb) {
        if (kb < 7) stageV(sV + ((kb + 1) & 1) * (F * 64), kb + 1);
        const float* buf = sV + (kb & 1) * (F * 64);
        #pragma unroll 4
        for (int kg = 0; kg < 16; ++kg) {
            const int k = kg * 4;
            float4 x0 = *(const float4*)&sA[(r0 + 0) * 512 + kb * 64 + k];
            float4 x1 = *(const float4*)&sA[(r0 + 1) * 512 + kb * 64 + k];
            float4 v0 = *(const float4*)&buf[c0 * 64 + (k ^ sw0)];
            float4 v1 = *(const float4*)&buf[c1 * 64 + (k ^ sw1)];
            a00 = fmaf(x0.x, v0.x, a00); a00 = fmaf(x0.y, v0.y, a00);
            a00 = fmaf(x0.z, v0.z, a00); a00 = fmaf(x0.w, v0.w, a00);
            a01 = fmaf(x0.x, v1.x, a01); a01 = fmaf(x0.y, v1.y, a01);
            a01 = fmaf(x0.z, v1.z, a01); a01 = fmaf(x0.w, v1.w, a01);
            a10 = fmaf(x1.x, v0.x, a10); a10 = fmaf(x1.y, v0.y, a10);
            a10 = fmaf(x1.z, v0.z, a10); a10 = fmaf(x1.w, v0.w, a10);
            a11 = fmaf(x1.x, v1.x, a11); a11 = fmaf(x1.y, v1.y, a11);
            a11 = fmaf(x1.z, v1.z, a11); a11 = fmaf(x1.w, v1.w, a11);
        }
        __syncthreads();
    }
    sC[(r0 + 0) * SC + c0] = a00; sC[(r0 + 0) * SC + c1] = a01;
    sC[(r0 + 1) * SC + c0] = a10; sC[(r0 + 1) * SC + c1] = a11;
    __syncthreads();

    // ---- epilogues: lane=f; chains bit-identical to R11 ----
    if constexpr (STAGE == 1) {
        const int sel = tid >> 6, f = tid & 63;   // wave = gate
        const float* W = sel ? Wr1 : Wz1;
        float d[8];
        #pragma unroll
        for (int i = 0; i < 8; ++i) d[i] = 0.f;
        #pragma unroll 4
        for (int kq = 0; kq < 16; ++kq) {   // U part: k = 0..63
            float4 u[8];
            #pragma unroll
            for (int i = 0; i < 8; ++i) u[i] = *(const float4*)&sUX[i * 68 + kq * 4];
            const float* Wp = W + (kq * 4) * 64 + f;
            float w0 = Wp[0], w1 = Wp[64], w2 = Wp[128], w3 = Wp[192];
            #pragma unroll
            for (int i = 0; i < 8; ++i) d[i] = fmaf(u[i].x, w0, d[i]);
            #pragma unroll
            for (int i = 0; i < 8; ++i) d[i] = fmaf(u[i].y, w1, d[i]);
            #pragma unroll
            for (int i = 0; i < 8; ++i) d[i] = fmaf(u[i].z, w2, d[i]);
            #pragma unroll
            for (int i = 0; i < 8; ++i) d[i] = fmaf(u[i].w, w3, d[i]);
        }
        #pragma unroll 4
        for (int kq = 0; kq < 16; ++kq) {   // C part: W rows 64..127
            float4 cv[8];
            #pragma unroll
            for (int i = 0; i < 8; ++i) cv[i] = *(const float4*)&sC[i * SC + kq * 4];
            const float* Wp = W + (64 + kq * 4) * 64 + f;
            float w0 = Wp[0], w1 = Wp[64], w2 = Wp[128], w3 = Wp[192];
            #pragma unroll
            for (int i = 0; i < 8; ++i) d[i] = fmaf(cv[i].x, w0, d[i]);
            #pragma unroll
            for (int i = 0; i < 8; ++i) d[i] = fmaf(cv[i].y, w1, d[i]);
            #pragma unroll
            for (int i = 0; i < 8; ++i) d[i] = fmaf(cv[i].z, w2, d[i]);
            #pragma unroll
            for (int i = 0; i < 8; ++i) d[i] = fmaf(cv[i].w, w3, d[i]);
        }
        float* dstT = (sel ? hrT : hzT) + (size_t)b * 64 * N_ + (size_t)f * N_ + m0;
        *(float4*)(dstT) =
            make_float4(fmaxf(d[0], 0.f), fmaxf(d[1], 0.f), fmaxf(d[2], 0.f), fmaxf(d[3], 0.f));
        *(float4*)(dstT + 4) =
            make_float4(fmaxf(d[4], 0.f), fmaxf(d[5], 0.f), fmaxf(d[6], 0.f), fmaxf(d[7], 0.f));
    }

    if constexpr (STAGE == 2) {
        const int sel = tid >> 7, f = tid & 63, ng = (tid >> 6) & 1, n0 = ng * 4;
        const float* W = sel ? Wr2 : Wz2;
        const int off = sel * 64;
        float d[4] = {0.f, 0.f, 0.f, 0.f};
        #pragma unroll 4
        for (int kq = 0; kq < 16; ++kq) {
            float4 c0_ = *(const float4*)&sC[(n0 + 0) * SC + off + kq * 4];
            float4 c1_ = *(const float4*)&sC[(n0 + 1) * SC + off + kq * 4];
            float4 c2_ = *(const float4*)&sC[(n0 + 2) * SC + off + kq * 4];
            float4 c3_ = *(const float4*)&sC[(n0 + 3) * SC + off + kq * 4];
            const float* Wp = W + (kq * 4) * 64 + f;
            float w0 = Wp[0], w1 = Wp[64], w2 = Wp[128], w3 = Wp[192];
            d[0]=fmaf(c0_.x,w0,d[0]); d[1]=fmaf(c1_.x,w0,d[1]); d[2]=fmaf(c2_.x,w0,d[2]); d[3]=fmaf(c3_.x,w0,d[3]);
            d[0]=fmaf(c0_.y,w1,d[0]); d[1]=fmaf(c1_.y,w1,d[1]); d[2]=fmaf(c2_.y,w1,d[2]); d[3]=fmaf(c3_.y,w1,d[3]);
            d[0]=fmaf(c0_.z,w2,d[0]); d[1]=fmaf(c1_.z,w2,d[1]); d[2]=fmaf(c2_.z,w2,d[2]); d[3]=fmaf(c3_.z,w2,d[3]);
            d[0]=fmaf(c0_.w,w3,d[0]); d[1]=fmaf(c1_.w,w3,d[1]); d[2]=fmaf(c2_.w,w3,d[2]); d[3]=fmaf(c3_.w,w3,d[3]);
        }
        if (!sel) {
            *(float4*)(zT + ((size_t)b * 64 + f) * N_ + m0 + n0) =
                make_float4(fsig(d[0]), fsig(d[1]), fsig(d[2]), fsig(d[3]));
        } else {
            float4 h4 = *(const float4*)(hT + ((size_t)b * 64 + f) * N_ + m0 + n0);
            *(float4*)(rhT + ((size_t)b * 64 + f) * N_ + m0 + n0) =
                make_float4(__fmul_rn(fsig(d[0]), h4.x), __fmul_rn(fsig(d[1]), h4.y),
                            __fmul_rn(fsig(d[2]), h4.z), __fmul_rn(fsig(d[3]), h4.w));
        }
    }

    if constexpr (STAGE == 3) {
        const int w = tid >> 6, f = tid & 63, n0 = w * 4;
        float d[4] = {0.f, 0.f, 0.f, 0.f};
        #pragma unroll 4
        for (int kq = 0; kq < 16; ++kq) {   // U part
            float4 u0 = *(const float4*)&sUX[(n0 + 0) * 68 + kq * 4];
            float4 u1 = *(const float4*)&sUX[(n0 + 1) * 68 + kq * 4];
            float4 u2 = *(const float4*)&sUX[(n0 + 2) * 68 + kq * 4];
            float4 u3 = *(const float4*)&sUX[(n0 + 3) * 68 + kq * 4];
            const float* Wp = Wc1 + (kq * 4) * 64 + f;
            float w0 = Wp[0], w1 = Wp[64], w2 = Wp[128], w3 = Wp[192];
            d[0]=fmaf(u0.x,w0,d[0]); d[1]=fmaf(u1.x,w0,d[1]); d[2]=fmaf(u2.x,w0,d[2]); d[3]=fmaf(u3.x,w0,d[3]);
            d[0]=fmaf(u0.y,w1,d[0]); d[1]=fmaf(u1.y,w1,d[1]); d[2]=fmaf(u2.y,w1,d[2]); d[3]=fmaf(u3.y,w1,d[3]);
            d[0]=fmaf(u0.z,w2,d[0]); d[1]=fmaf(u1.z,w2,d[1]); d[2]=fmaf(u2.z,w2,d[2]); d[3]=fmaf(u3.z,w2,d[3]);
            d[0]=fmaf(u0.w,w3,d[0]); d[1]=fmaf(u1.w,w3,d[1]); d[2]=fmaf(u2.w,w3,d[2]); d[3]=fmaf(u3.w,w3,d[3]);
        }
        #pragma unroll 4
        for (int kq = 0; kq < 16; ++kq) {   // C part, W rows 64..127
            float4 c0_ = *(const float4*)&sC[(n0 + 0) * SC + kq * 4];
            float4 c1_ = *(const float4*)&sC[(n0 + 1) * SC + kq * 4];
            float4 c2_ = *(const float4*)&sC[(n0 + 2) * SC + kq * 4];
            float4 c3_ = *(const float4*)&sC[(n0 + 3) * SC + kq * 4];
            const float* Wp = Wc1 + (64 + kq * 4) * 64 + f;
            float w0 = Wp[0], w1 = Wp[64], w2 = Wp[128], w3 = Wp[192];
            d[0]=fmaf(c0_.x,w0,d[0]); d[1]=fmaf(c1_.x,w0,d[1]); d[2]=fmaf(c2_.x,w0,d[2]); d[3]=fmaf(c3_.x,w0,d[3]);
            d[0]=fmaf(c0_.y,w1,d[0]); d[1]=fmaf(c1_.y,w1,d[1]); d[2]=fmaf(c2_.y,w1,d[2]); d[3]=fmaf(c3_.y,w1,d[3]);
            d[0]=fmaf(c0_.z,w2,d[0]); d[1]=fmaf(c1_.z,w2,d[1]); d[2]=fmaf(c2_.z,w2,d[2]); d[3]=fmaf(c3_.z,w2,d[3]);
            d[0]=fmaf(c0_.w,w3,d[0]); d[1]=fmaf(c1_.w,w3,d[1]); d[2]=fmaf(c2_.w,w3,d[2]); d[3]=fmaf(c3_.w,w3,d[3]);
        }
        *(float4*)(hcT + ((size_t)b * 64 + f) * N_ + m0 + n0) =
            make_float4(fmaxf(d[0], 0.f), fmaxf(d[1], 0.f), fmaxf(d[2], 0.f), fmaxf(d[3], 0.f));
    }

    if constexpr (STAGE == 4) {
        const int w = tid >> 6, f = tid & 63, n0 = w * 4;
        float d[4] = {0.f, 0.f, 0.f, 0.f};
        #pragma unroll 4
        for (int kq = 0; kq < 16; ++kq) {
            float4 c0_ = *(const float4*)&sC[(n0 + 0) * SC + kq * 4];
            float4 c1_ = *(const float4*)&sC[(n0 + 1) * SC + kq * 4];
            float4 c2_ = *(const float4*)&sC[(n0 + 2) * SC + kq * 4];
            float4 c3_ = *(const float4*)&sC[(n0 + 3) * SC + kq * 4];
            const float* Wp = Wc2 + (kq * 4) * 64 + f;
            float w0 = Wp[0], w1 = Wp[64], w2 = Wp[128], w3 = Wp[192];
            d[0]=fmaf(c0_.x,w0,d[0]); d[1]=fmaf(c1_.x,w0,d[1]); d[2]=fmaf(c2_.x,w0,d[2]); d[3]=fmaf(c3_.x,w0,d[3]);
            d[0]=fmaf(c0_.y,w1,d[0]); d[1]=fmaf(c1_.y,w1,d[1]); d[2]=fmaf(c2_.y,w1,d[2]); d[3]=fmaf(c3_.y,w1,d[3]);
            d[0]=fmaf(c0_.z,w2,d[0]); d[1]=fmaf(c1_.z,w2,d[1]); d[2]=fmaf(c2_.z,w2,d[2]); d[3]=fmaf(c3_.z,w2,d[3]);
            d[0]=fmaf(c0_.w,w3,d[0]); d[1]=fmaf(c1_.w,w3,d[1]); d[2]=fmaf(c2_.w,w3,d[2]); d[3]=fmaf(c3_.w,w3,d[3]);
        }
        float cg0 = ftanh(d[0]), cg1 = ftanh(d[1]), cg2 = ftanh(d[2]), cg3 = ftanh(d[3]);
        float* hp = hT + ((size_t)b * 64 + f) * N_ + m0 + n0;
        float4 h4 = *(const float4*)hp;
        float4 z4 = *(const float4*)(zT + ((size_t)b * 64 + f) * N_ + m0 + n0);
        float hh[4] = {h4.x, h4.y, h4.z, h4.w};
        float zz[4] = {z4.x, z4.y, z4.z, z4.w};
        float cc[4] = {cg0, cg1, cg2, cg3};
        float hn[4];
        #pragma unroll
        for (int i = 0; i < 4; ++i) {
            float t1 = __fmul_rn(zz[i], hh[i]);
            float om = __fsub_rn(1.0f, zz[i]);
            float t2 = __fmul_rn(om, cc[i]);
            hn[i] = __fadd_rn(t1, t2);
        }
        *(float4*)hp = make_float4(hn[0], hn[1], hn[2], hn[3]);
        #pragma unroll
        for (int i = 0; i < 4; ++i)
            out[((size_t)bt * N_ + m0 + n0 + i) * 64 + f] = hn[i];
    }
    (void)s1;
}

// ================= launch =================

extern "C" void kernel_launch(void* const* d_in, const int* in_sizes, int n_in,
                              void* d_out, int out_size, void* d_ws, size_t ws_size,
                              hipStream_t stream) {
    (void)in_sizes; (void)n_in; (void)out_size; (void)ws_size;
    const float* x    = (const float*)d_in[0];
    const float* e    = (const float*)d_in[1];
    const float* fc_w = (const float*)d_in[2];
    const float* fc_b = (const float*)d_in[3];
    const float* Wz1  = (const float*)d_in[4];
    const float* Wz2  = (const float*)d_in[5];
    const float* Wr1  = (const float*)d_in[6];
    const float* Wr2  = (const float*)d_in[7];
    const float* Wc1  = (const float*)d_in[8];
    const float* Wc2  = (const float*)d_in[9];
    float* out = (float*)d_out;

    char* p = (char*)d_ws;
    auto alloc = [&](size_t bytes) { char* r = p; p += (bytes + 255) & ~(size_t)255; return r; };
    const size_t HSZ = (size_t)B_ * 64 * N_ * 4;
    float* xpT = (float*)alloc((size_t)B_ * T_ * 64 * N_ * 4);
    float* UX  = (float*)alloc((size_t)B_ * T_ * N_ * 64 * 4);
    float* hT  = (float*)alloc(HSZ);
    float* hzT = (float*)alloc(HSZ);
    float* hrT = (float*)alloc(HSZ);
    float* zT  = (float*)alloc(HSZ);
    float* rhT = (float*)alloc(HSZ);
    float* hcT = (float*)alloc(HSZ);

    xpT_kernel<<<dim3(8, B_ * T_), 256, 0, stream>>>(x, fc_w, fc_b, xpT);
    ux_kernel<<<dim3(8, B_ * T_), 256, 0, stream>>>(e, xpT, UX);
    hipMemsetAsync(hT, 0, HSZ, stream);

    dim3 grid(N_ / 8, B_);
    for (int t = 0; t < T_; ++t) {
        stage_kernel<1><<<grid, 128, 0, stream>>>(e, t, UX, Wz1, Wz2, Wr1, Wr2, Wc1, Wc2,
                                                  hT, hzT, hrT, zT, rhT, hcT, out);
        stage_kernel<2><<<grid, 256, 0, stream>>>(e, t, UX, Wz1, Wz2, Wr1, Wr2, Wc1, Wc2,
                                                  hT, hzT, hrT, zT, rhT, hcT, out);
        stage_kernel<3><<<grid, 128, 0, stream>>>(e, t, UX, Wz1, Wz2, Wr1, Wr2, Wc1, Wc2,
                                                  hT, hzT, hrT, zT, rhT, hcT, out);
        stage_kernel<4><<<grid, 128, 0, stream>>>(e, t, UX, Wz1, Wz2, Wr1, Wr2, Wc1, Wc2,
                                                  hT, hzT, hrT, zT, rhT, hcT, out);
    }
}

// Round 13
// 1506.663 us; speedup vs baseline: 1.3481x; 1.3481x over previous
//
#include <hip/hip_runtime.h>
#include <cstdint>
#include <cstddef>

#define B_ 4
#define T_ 24
#define N_ 512

// gate nonlinearities: evaluate in f64, round once to f32 (R4-proven numerics)
__device__ __forceinline__ float fsig(float x)  { return (float)(1.0 / (1.0 + exp(-(double)x))); }
__device__ __forceinline__ float ftanh(float x) { return (float)tanh((double)x); }

// 16-slot XOR swizzle for [F][64] LDS tiles (R7-proven)
__device__ __forceinline__ int swz16(int f) { return (((f & 15) ^ ((f >> 4) & 15)) << 2); }

// ================= PRECOMPUTE (parallel, recurrence-free) =================

// xp = relu(x @ fc_w + fc_b), stored feature-major xpT[bt][f][node]
__global__ __launch_bounds__(256) void xpT_kernel(const float* __restrict__ x,
                                                  const float* __restrict__ fc_w,
                                                  const float* __restrict__ fc_b,
                                                  float* __restrict__ xpT) {
    __shared__ __align__(16) float sX[64 * 68];
    __shared__ __align__(16) float sW[64 * 64];
    __shared__ float sB[64];
    const int bt = blockIdx.y;
    const int n0 = blockIdx.x * 64;
    const int tid = threadIdx.x;
    for (int i = tid * 4; i < 4096; i += 1024)
        *(float4*)&sW[i] = *(const float4*)&fc_w[i];
    if (tid < 64) sB[tid] = fc_b[tid];
    {
        int r = tid >> 2, kq = (tid & 3) * 16;
        const float* p = x + ((size_t)bt * N_ + n0 + r) * 64 + kq;
        #pragma unroll
        for (int j = 0; j < 4; ++j)
            *(float4*)&sX[r * 68 + kq + j * 4] = *(const float4*)(p + j * 4);
    }
    __syncthreads();
    const int f = tid & 63, ng = tid >> 6;
    float d[16];
    #pragma unroll
    for (int j = 0; j < 16; ++j) d[j] = 0.f;
    for (int k = 0; k < 64; ++k) {
        float w = sW[k * 64 + f];
        #pragma unroll
        for (int j = 0; j < 16; ++j)
            d[j] = fmaf(sX[(ng * 16 + j) * 68 + k], w, d[j]);
    }
    const float bias = sB[f];
    float* o = xpT + ((size_t)bt * 64 + f) * N_ + n0 + ng * 16;
    #pragma unroll
    for (int j = 0; j < 16; ++j)
        o[j] = fmaxf(__fadd_rn(d[j], bias), 0.f);
}

// UX[bt][node][64] = (A_bt @ xp_bt): 64x64 block tile, 4x4 register tiling (R11-proven)
__global__ __launch_bounds__(256) void ux_kernel(const float* __restrict__ e,
                                                 const float* __restrict__ xpT,
                                                 float* __restrict__ UX) {
    __shared__ __align__(16) float sA[2][64 * 72];
    __shared__ __align__(16) float sV[2][64 * 64];
    const int bt = blockIdx.y;
    const int m0 = blockIdx.x * 64;
    const int tid = threadIdx.x;
    const float* Ab = e + ((size_t)bt * N_ + m0) * N_;
    const float* s0 = xpT + (size_t)bt * 64 * N_;

    auto stageA = [&](float* dst, int kt) {
        const int r = tid >> 2, kq = (tid & 3) * 16;
        const float* src = Ab + (size_t)r * N_ + kt * 64 + kq;
        float* d = dst + r * 72 + kq;
        #pragma unroll
        for (int j = 0; j < 4; ++j)
            *(float4*)(d + j * 4) = *(const float4*)(src + j * 4);
    };
    auto stageV = [&](float* dst, int kt) {
        const int f = tid >> 2, q = tid & 3;
        const int sw = swz16(f);
        const float* src = s0 + (size_t)f * N_ + kt * 64;
        #pragma unroll
        for (int j = 0; j < 4; ++j) {
            int k = q * 16 + j * 4;
            *(float4*)&dst[f * 64 + (k ^ sw)] = *(const float4*)(src + k);
        }
    };

    stageA(sA[0], 0);
    stageV(sV[0], 0);
    __syncthreads();

    const int cg = tid & 15, rg = tid >> 4;
    const int c0 = cg * 4;
    float acc[4][4];
    #pragma unroll
    for (int i = 0; i < 4; ++i)
        #pragma unroll
        for (int j = 0; j < 4; ++j) acc[i][j] = 0.f;

    for (int kb = 0; kb < 8; ++kb) {
        if (kb < 7) { stageA(sA[(kb + 1) & 1], kb + 1); stageV(sV[(kb + 1) & 1], kb + 1); }
        const float* Ab_ = sA[kb & 1];
        const float* Vb_ = sV[kb & 1];
        #pragma unroll 4
        for (int kg = 0; kg < 16; ++kg) {
            const int k = kg * 4;
            float4 v[4], a[4];
            #pragma unroll
            for (int j = 0; j < 4; ++j)
                v[j] = *(const float4*)&Vb_[(c0 + j) * 64 + (k ^ swz16(c0 + j))];
            #pragma unroll
            for (int i = 0; i < 4; ++i)
                a[i] = *(const float4*)&Ab_[(rg * 4 + i) * 72 + k];
            #pragma unroll
            for (int i = 0; i < 4; ++i)
                #pragma unroll
                for (int j = 0; j < 4; ++j) {
                    acc[i][j] = fmaf(a[i].x, v[j].x, acc[i][j]);
                    acc[i][j] = fmaf(a[i].y, v[j].y, acc[i][j]);
                    acc[i][j] = fmaf(a[i].z, v[j].z, acc[i][j]);
                    acc[i][j] = fmaf(a[i].w, v[j].w, acc[i][j]);
                }
        }
        __syncthreads();
    }
    #pragma unroll
    for (int i = 0; i < 4; ++i)
        *(float4*)&UX[((size_t)bt * N_ + m0 + rg * 4 + i) * 64 + c0] =
            make_float4(acc[i][0], acc[i][1], acc[i][2], acc[i][3]);
}

// ================= STAGE KERNELS (BM=8, 256 blocks, 512 threads = 2 waves/SIMD) =================
// S1: C = A@h;        hz = relu([UX|C]@Wz1); hr = relu([UX|C]@Wr1)
// S2: C = A@[hz|hr];  z = sig(C_z@Wz2) -> zT; rh = sig(C_r@Wr2)*h
// S3: C = A@rh;       hc = relu(UX@Wc1_top + C@Wc1_bot)
// S4: C = A@hc;       c = tanh(C@Wc2); hn = z*h + (1-z)*c -> hT, out
template <int STAGE>
__global__ __launch_bounds__(512, 1) void stage_kernel(
    const float* __restrict__ e, int t,
    const float* __restrict__ UX,
    const float* __restrict__ Wz1, const float* __restrict__ Wz2,
    const float* __restrict__ Wr1, const float* __restrict__ Wr2,
    const float* __restrict__ Wc1, const float* __restrict__ Wc2,
    float* __restrict__ hT, float* __restrict__ hzT, float* __restrict__ hrT,
    float* __restrict__ zT, float* __restrict__ rhT, float* __restrict__ hcT,
    float* __restrict__ out)
{
    constexpr int F = (STAGE == 2) ? 128 : 64;
    constexpr int SC = F + 4;
    __shared__ __align__(16) float sA[8 * 512];          // 16 KB
    __shared__ __align__(16) float sV[2 * F * 64];       // 64 KB (F=128) / 32 KB
    __shared__ __align__(16) float sC[8 * SC];
    __shared__ __align__(16) float sUX[8 * 68];

    const int b = blockIdx.y;
    const int m0 = blockIdx.x * 8;
    const int tid = threadIdx.x;
    const int lane = tid & 63;
    const int bt = b * T_ + t;

    const float* Ab = e + ((size_t)bt * N_ + m0) * N_;

    const float* s0;
    const float* s1 = nullptr;
    if (STAGE == 1)      { s0 = hT  + (size_t)b * 64 * N_; }
    else if (STAGE == 2) { s0 = hzT + (size_t)b * 64 * N_; s1 = hrT + (size_t)b * 64 * N_; }
    else if (STAGE == 3) { s0 = rhT + (size_t)b * 64 * N_; }
    else                 { s0 = hcT + (size_t)b * 64 * N_; }

    {   // stage A rows [8][512]: 1024 float4 over 512 threads -> 2 each
        const int r = tid >> 6, seg = (tid & 63) * 8;
        const float* src = Ab + (size_t)r * N_ + seg;
        float* dst = sA + r * 512 + seg;
        *(float4*)(dst)     = *(const float4*)(src);
        *(float4*)(dst + 4) = *(const float4*)(src + 4);
    }
    if constexpr (STAGE == 1 || STAGE == 3) {
        if (tid < 128) {    // stage UX tile [8][64]: 128 float4
            const int n = tid >> 4, q = (tid & 15) * 4;
            *(float4*)&sUX[n * 68 + q] =
                *(const float4*)&UX[((size_t)bt * N_ + m0 + n) * 64 + q];
        }
    }

    auto stageV = [&](float* dst, int kt) {
        if constexpr (F == 128) {
            // 2048 float4 over 512 threads -> 4 each
            const int f = tid >> 2, q = tid & 3;
            const float* src = ((f < 64) ? (s0 + (size_t)f * N_)
                                         : (s1 + (size_t)(f - 64) * N_)) + kt * 64 + q * 16;
            const int sw = swz16(f);
            #pragma unroll
            for (int j = 0; j < 4; ++j)
                *(float4*)&dst[f * 64 + ((q * 16 + j * 4) ^ sw)] = *(const float4*)(src + j * 4);
        } else {
            // 1024 float4 over 512 threads -> 2 each
            const int f = tid >> 3, o = tid & 7;
            const float* src = s0 + (size_t)f * N_ + kt * 64 + o * 8;
            const int sw = swz16(f);
            #pragma unroll
            for (int j = 0; j < 2; ++j)
                *(float4*)&dst[f * 64 + ((o * 8 + j * 4) ^ sw)] = *(const float4*)(src + j * 4);
        }
    };

    // ---- conv: C = A @ V. wave = row (rg=tid>>6), double-buffered, ascending-k chains ----
    const int rr = tid >> 6;          // row 0..7 (one per wave)
    const int c0 = lane;              // col 0..63
    const int sw0 = swz16(c0);
    float a0 = 0.f, a1 = 0.f;         // F=128: cols (lane, lane+64); F=64: a1 unused
    const int c1 = lane + 64;
    const int sw1 = swz16(c1);

    stageV(sV, 0);
    __syncthreads();
    for (int kb = 0; kb < 8; ++kb) {
        if (kb < 7) stageV(sV + ((kb + 1) & 1) * (F * 64), kb + 1);
        const float* buf = sV + (kb & 1) * (F * 64);
        #pragma unroll 4
        for (int kg = 0; kg < 16; ++kg) {
            const int k = kg * 4;
            float4 x = *(const float4*)&sA[rr * 512 + kb * 64 + k];
            float4 v0 = *(const float4*)&buf[c0 * 64 + (k ^ sw0)];
            a0 = fmaf(x.x, v0.x, a0); a0 = fmaf(x.y, v0.y, a0);
            a0 = fmaf(x.z, v0.z, a0); a0 = fmaf(x.w, v0.w, a0);
            if constexpr (F == 128) {
                float4 v1 = *(const float4*)&buf[c1 * 64 + (k ^ sw1)];
                a1 = fmaf(x.x, v1.x, a1); a1 = fmaf(x.y, v1.y, a1);
                a1 = fmaf(x.z, v1.z, a1); a1 = fmaf(x.w, v1.w, a1);
            }
        }
        __syncthreads();
    }
    sC[rr * SC + c0] = a0;
    if constexpr (F == 128) sC[rr * SC + c1] = a1;
    __syncthreads();

    // ---- epilogues: per-output ascending-k chains, bit-identical to R11 ----
    if constexpr (STAGE == 1) {
        const int sel = tid >> 8, f = lane, ng = (tid >> 6) & 3, n0 = ng * 2;
        const float* W = sel ? Wr1 : Wz1;
        float d0 = 0.f, d1 = 0.f;
        #pragma unroll 4
        for (int kq = 0; kq < 16; ++kq) {   // U part: k = 0..63
            float4 u0 = *(const float4*)&sUX[(n0 + 0) * 68 + kq * 4];
            float4 u1 = *(const float4*)&sUX[(n0 + 1) * 68 + kq * 4];
            const float* Wp = W + (kq * 4) * 64 + f;
            float w0 = Wp[0], w1 = Wp[64], w2 = Wp[128], w3 = Wp[192];
            d0 = fmaf(u0.x, w0, d0); d1 = fmaf(u1.x, w0, d1);
            d0 = fmaf(u0.y, w1, d0); d1 = fmaf(u1.y, w1, d1);
            d0 = fmaf(u0.z, w2, d0); d1 = fmaf(u1.z, w2, d1);
            d0 = fmaf(u0.w, w3, d0); d1 = fmaf(u1.w, w3, d1);
        }
        #pragma unroll 4
        for (int kq = 0; kq < 16; ++kq) {   // C part: W rows 64..127
            float4 c0_ = *(const float4*)&sC[(n0 + 0) * SC + kq * 4];
            float4 c1_ = *(const float4*)&sC[(n0 + 1) * SC + kq * 4];
            const float* Wp = W + (64 + kq * 4) * 64 + f;
            float w0 = Wp[0], w1 = Wp[64], w2 = Wp[128], w3 = Wp[192];
            d0 = fmaf(c0_.x, w0, d0); d1 = fmaf(c1_.x, w0, d1);
            d0 = fmaf(c0_.y, w1, d0); d1 = fmaf(c1_.y, w1, d1);
            d0 = fmaf(c0_.z, w2, d0); d1 = fmaf(c1_.z, w2, d1);
            d0 = fmaf(c0_.w, w3, d0); d1 = fmaf(c1_.w, w3, d1);
        }
        float* dstT = (sel ? hrT : hzT) + (size_t)b * 64 * N_ + (size_t)f * N_ + m0 + n0;
        *(float2*)dstT = make_float2(fmaxf(d0, 0.f), fmaxf(d1, 0.f));
    }

    if constexpr (STAGE == 2) {
        const int sel = tid >> 8, f = lane, ng = (tid >> 6) & 3, n0 = ng * 2;
        const float* W = sel ? Wr2 : Wz2;
        const int off = sel * 64;
        float d0 = 0.f, d1 = 0.f;
        #pragma unroll 4
        for (int kq = 0; kq < 16; ++kq) {
            float4 c0_ = *(const float4*)&sC[(n0 + 0) * SC + off + kq * 4];
            float4 c1_ = *(const float4*)&sC[(n0 + 1) * SC + off + kq * 4];
            const float* Wp = W + (kq * 4) * 64 + f;
            float w0 = Wp[0], w1 = Wp[64], w2 = Wp[128], w3 = Wp[192];
            d0 = fmaf(c0_.x, w0, d0); d1 = fmaf(c1_.x, w0, d1);
            d0 = fmaf(c0_.y, w1, d0); d1 = fmaf(c1_.y, w1, d1);
            d0 = fmaf(c0_.z, w2, d0); d1 = fmaf(c1_.z, w2, d1);
            d0 = fmaf(c0_.w, w3, d0); d1 = fmaf(c1_.w, w3, d1);
        }
        if (!sel) {
            *(float2*)(zT + ((size_t)b * 64 + f) * N_ + m0 + n0) =
                make_float2(fsig(d0), fsig(d1));
        } else {
            float2 h2 = *(const float2*)(hT + ((size_t)b * 64 + f) * N_ + m0 + n0);
            *(float2*)(rhT + ((size_t)b * 64 + f) * N_ + m0 + n0) =
                make_float2(__fmul_rn(fsig(d0), h2.x), __fmul_rn(fsig(d1), h2.y));
        }
    }

    if constexpr (STAGE == 3) {
        const int n = tid >> 6, f = lane;
        float d0 = 0.f;
        #pragma unroll 4
        for (int kq = 0; kq < 16; ++kq) {   // U part
            float4 u0 = *(const float4*)&sUX[n * 68 + kq * 4];
            const float* Wp = Wc1 + (kq * 4) * 64 + f;
            d0 = fmaf(u0.x, Wp[0], d0);
            d0 = fmaf(u0.y, Wp[64], d0);
            d0 = fmaf(u0.z, Wp[128], d0);
            d0 = fmaf(u0.w, Wp[192], d0);
        }
        #pragma unroll 4
        for (int kq = 0; kq < 16; ++kq) {   // C part, W rows 64..127
            float4 c0_ = *(const float4*)&sC[n * SC + kq * 4];
            const float* Wp = Wc1 + (64 + kq * 4) * 64 + f;
            d0 = fmaf(c0_.x, Wp[0], d0);
            d0 = fmaf(c0_.y, Wp[64], d0);
            d0 = fmaf(c0_.z, Wp[128], d0);
            d0 = fmaf(c0_.w, Wp[192], d0);
        }
        hcT[((size_t)b * 64 + f) * N_ + m0 + n] = fmaxf(d0, 0.f);
    }

    if constexpr (STAGE == 4) {
        const int n = tid >> 6, f = lane;
        float d0 = 0.f;
        #pragma unroll 4
        for (int kq = 0; kq < 16; ++kq) {
            float4 c0_ = *(const float4*)&sC[n * SC + kq * 4];
            const float* Wp = Wc2 + (kq * 4) * 64 + f;
            d0 = fmaf(c0_.x, Wp[0], d0);
            d0 = fmaf(c0_.y, Wp[64], d0);
            d0 = fmaf(c0_.z, Wp[128], d0);
            d0 = fmaf(c0_.w, Wp[192], d0);
        }
        float cg = ftanh(d0);
        float* hp = hT + ((size_t)b * 64 + f) * N_ + m0 + n;
        float h = *hp;
        float z = zT[((size_t)b * 64 + f) * N_ + m0 + n];
        float t1 = __fmul_rn(z, h);
        float om = __fsub_rn(1.0f, z);
        float t2 = __fmul_rn(om, cg);
        float hn = __fadd_rn(t1, t2);
        *hp = hn;
        out[((size_t)bt * N_ + m0 + n) * 64 + f] = hn;
    }
    (void)s1;
}

// ================= launch =================

extern "C" void kernel_launch(void* const* d_in, const int* in_sizes, int n_in,
                              void* d_out, int out_size, void* d_ws, size_t ws_size,
                              hipStream_t stream) {
    (void)in_sizes; (void)n_in; (void)out_size; (void)ws_size;
    const float* x    = (const float*)d_in[0];
    const float* e    = (const float*)d_in[1];
    const float* fc_w = (const float*)d_in[2];
    const float* fc_b = (const float*)d_in[3];
    const float* Wz1  = (const float*)d_in[4];
    const float* Wz2  = (const float*)d_in[5];
    const float* Wr1  = (const float*)d_in[6];
    const float* Wr2  = (const float*)d_in[7];
    const float* Wc1  = (const float*)d_in[8];
    const float* Wc2  = (const float*)d_in[9];
    float* out = (float*)d_out;

    char* p = (char*)d_ws;
    auto alloc = [&](size_t bytes) { char* r = p; p += (bytes + 255) & ~(size_t)255; return r; };
    const size_t HSZ = (size_t)B_ * 64 * N_ * 4;
    float* xpT = (float*)alloc((size_t)B_ * T_ * 64 * N_ * 4);
    float* UX  = (float*)alloc((size_t)B_ * T_ * N_ * 64 * 4);
    float* hT  = (float*)alloc(HSZ);
    float* hzT = (float*)alloc(HSZ);
    float* hrT = (float*)alloc(HSZ);
    float* zT  = (float*)alloc(HSZ);
    float* rhT = (float*)alloc(HSZ);
    float* hcT = (float*)alloc(HSZ);

    xpT_kernel<<<dim3(8, B_ * T_), 256, 0, stream>>>(x, fc_w, fc_b, xpT);
    ux_kernel<<<dim3(8, B_ * T_), 256, 0, stream>>>(e, xpT, UX);
    hipMemsetAsync(hT, 0, HSZ, stream);

    dim3 grid(N_ / 8, B_);
    for (int t = 0; t < T_; ++t) {
        stage_kernel<1><<<grid, 512, 0, stream>>>(e, t, UX, Wz1, Wz2, Wr1, Wr2, Wc1, Wc2,
                                                  hT, hzT, hrT, zT, rhT, hcT, out);
        stage_kernel<2><<<grid, 512, 0, stream>>>(e, t, UX, Wz1, Wz2, Wr1, Wr2, Wc1, Wc2,
                                                  hT, hzT, hrT, zT, rhT, hcT, out);
        stage_kernel<3><<<grid, 512, 0, stream>>>(e, t, UX, Wz1, Wz2, Wr1, Wr2, Wc1, Wc2,
                                                  hT, hzT, hrT, zT, rhT, hcT, out);
        stage_kernel<4><<<grid, 512, 0, stream>>>(e, t, UX, Wz1, Wz2, Wr1, Wr2, Wc1, Wc2,
                                                  hT, hzT, hrT, zT, rhT, hcT, out);
    }
}